// Round 1
// baseline (5283.828 us; speedup 1.0000x reference)
//
#include <hip/hip_runtime.h>
#include <math.h>

#define H_SIZE 768
#define DEPTH 2
#define HEADS 12
#define HDIM 64
#define N_TOK 256
#define BATCH 4
#define TOKS (BATCH * N_TOK) /* 1024 */
#define E_NUM 8
#define TOPK 2
#define C_CAP 320
#define FFN_D 3072

// ---------------- patch embed + pos ----------------
__global__ void patch_kernel(const float* __restrict__ x, const float* __restrict__ Wpe,
                             const float* __restrict__ bpe, const float* __restrict__ pos,
                             float* __restrict__ h) {
    int bn = blockIdx.x;          // b*256 + n
    int b = bn >> 8, n = bn & 255;
    int hw1 = n >> 4, hw2 = n & 15;
    __shared__ float xv[16];
    if (threadIdx.x < 16) {
        int c = threadIdx.x >> 2, ph = (threadIdx.x >> 1) & 1, pw = threadIdx.x & 1;
        xv[threadIdx.x] = x[((b * 4 + c) * 32 + hw1 * 2 + ph) * 32 + hw2 * 2 + pw];
    }
    __syncthreads();
    for (int d = threadIdx.x; d < H_SIZE; d += 256) {
        float acc = bpe[d];
#pragma unroll
        for (int i = 0; i < 16; i++) acc += xv[i] * Wpe[d * 16 + i];
        h[(long)bn * H_SIZE + d] = acc + pos[n * H_SIZE + d];
    }
}

// ---------------- sinusoidal time embedding ----------------
__global__ void te_kernel(const float* __restrict__ t, float* __restrict__ te) {
    int i = blockIdx.x * 256 + threadIdx.x; // 4*768
    if (i >= BATCH * H_SIZE) return;
    int b = i / H_SIZE, d = i % H_SIZE;
    int dd = (d < 384) ? d : d - 384;
    float fr = expf(-logf(10000.f) * (float)dd / 384.f);
    float a = t[b] * fr;
    te[i] = (d < 384) ? sinf(a) : cosf(a);
}

__global__ void cond_kernel(const float* __restrict__ temb, const float* __restrict__ null_emb,
                            float* __restrict__ cond) {
    int i = blockIdx.x * 256 + threadIdx.x; // 3072
    if (i >= BATCH * H_SIZE) return;
    int d = i % H_SIZE;
    float v = temb[i] + null_emb[d];
    cond[i] = v / (1.f + expf(-v));
}

// ---------------- generic activations ----------------
__device__ __forceinline__ float apply_act(float x, int act) {
    if (act == 1) x = x / (1.f + expf(-x));                       // silu
    else if (act == 2) {                                          // gelu (tanh approx)
        float x3 = x * x * x;
        x = 0.5f * x * (1.f + tanhf(0.7978845608028654f * (x + 0.044715f * x3)));
    } else if (act == 3) x = 1.f / (1.f + expf(-x));              // sigmoid
    return x;
}

// ---------------- naive GEMM (small M*N) ----------------
__global__ void gemm_naive(const float* __restrict__ A, const float* __restrict__ W,
                           const float* __restrict__ bias, float* __restrict__ C,
                           int M, int N, int K, int act) {
    int idx = blockIdx.x * 256 + threadIdx.x;
    if (idx >= M * N) return;
    int m = idx / N, n = idx % N;
    float acc = bias ? bias[n] : 0.f;
    const float* a = A + (long)m * K;
    for (int kk = 0; kk < K; kk++) acc += a[kk] * W[(long)kk * N + n];
    C[idx] = apply_act(acc, act);
}

// ---------------- tiled f32 GEMM, 64x64 tile, 4x4 microtile ----------------
// requires M%64==0, N%64==0, K%16==0
__global__ __launch_bounds__(256) void gemm_tiled(
    const float* __restrict__ A, const float* __restrict__ W,
    const float* __restrict__ bias, float* __restrict__ C,
    int M, int N, int K, long aStr, long wStr, long bStr, long cStr, int act) {
    int e = blockIdx.z;
    A += (long)e * aStr; W += (long)e * wStr; C += (long)e * cStr;
    if (bias) bias += (long)e * bStr;
    int bm = blockIdx.y * 64, bn = blockIdx.x * 64;
    __shared__ float As[16][65];
    __shared__ float Ws[16][65];
    int tid = threadIdx.x;
    int tx = tid & 15, ty = tid >> 4;
    float acc[4][4] = {};
    for (int k0 = 0; k0 < K; k0 += 16) {
#pragma unroll
        for (int l = 0; l < 4; l++) {
            int li = tid + 256 * l;            // 0..1023
            int m = li >> 4, kk = li & 15;
            As[kk][m] = A[(long)(bm + m) * K + k0 + kk];
            int n = li & 63, kk2 = li >> 6;
            Ws[kk2][n] = W[(long)(k0 + kk2) * N + bn + n];
        }
        __syncthreads();
#pragma unroll
        for (int kk = 0; kk < 16; kk++) {
            float a[4], w[4];
#pragma unroll
            for (int i = 0; i < 4; i++) a[i] = As[kk][ty * 4 + i];
#pragma unroll
            for (int j = 0; j < 4; j++) w[j] = Ws[kk][tx * 4 + j];
#pragma unroll
            for (int i = 0; i < 4; i++)
#pragma unroll
                for (int j = 0; j < 4; j++) acc[i][j] += a[i] * w[j];
        }
        __syncthreads();
    }
#pragma unroll
    for (int i = 0; i < 4; i++) {
        int m = bm + ty * 4 + i;
#pragma unroll
        for (int j = 0; j < 4; j++) {
            int n = bn + tx * 4 + j;
            float xv = acc[i][j] + (bias ? bias[n] : 0.f);
            C[(long)m * N + n] = apply_act(xv, act);
        }
    }
}

// ---------------- layernorm + adaLN modulation ----------------
__global__ void ln_mod_kernel(const float* __restrict__ x, float* __restrict__ out,
                              const float* __restrict__ mod, int modStride, int sOff, int scOff) {
    int row = blockIdx.x;     // 0..1023
    int b = row >> 8;
    const float* xr = x + (long)row * H_SIZE;
    float v0 = xr[threadIdx.x], v1 = xr[threadIdx.x + 256], v2 = xr[threadIdx.x + 512];
    float s = v0 + v1 + v2, ss = v0 * v0 + v1 * v1 + v2 * v2;
    for (int off = 32; off; off >>= 1) {
        s += __shfl_down(s, off, 64);
        ss += __shfl_down(ss, off, 64);
    }
    __shared__ float red[2][4];
    int wid = threadIdx.x >> 6;
    if ((threadIdx.x & 63) == 0) { red[0][wid] = s; red[1][wid] = ss; }
    __syncthreads();
    s = red[0][0] + red[0][1] + red[0][2] + red[0][3];
    ss = red[1][0] + red[1][1] + red[1][2] + red[1][3];
    float mean = s * (1.f / 768.f);
    float var = ss * (1.f / 768.f) - mean * mean;
    float rstd = rsqrtf(var + 1e-6f);
    const float* sp = mod + (long)b * modStride + sOff;
    const float* scp = mod + (long)b * modStride + scOff;
    float* orow = out + (long)row * H_SIZE;
    orow[threadIdx.x] = (v0 - mean) * rstd * (1.f + scp[threadIdx.x]) + sp[threadIdx.x];
    orow[threadIdx.x + 256] = (v1 - mean) * rstd * (1.f + scp[threadIdx.x + 256]) + sp[threadIdx.x + 256];
    orow[threadIdx.x + 512] = (v2 - mean) * rstd * (1.f + scp[threadIdx.x + 512]) + sp[threadIdx.x + 512];
}

// ---------------- per-head L2 normalize q and k ----------------
__global__ void headnorm_kernel(float* __restrict__ q, float* __restrict__ k) {
    int g = blockIdx.x;             // tok*HEADS + head
    int tok = g / HEADS, hd = g % HEADS;
    long idx = (long)tok * H_SIZE + hd * HDIM + threadIdx.x;
    float qv = q[idx], kv = k[idx];
    float sq = qv * qv, sk = kv * kv;
    for (int off = 32; off; off >>= 1) {
        sq += __shfl_down(sq, off, 64);
        sk += __shfl_down(sk, off, 64);
    }
    sq = __shfl(sq, 0, 64); sk = __shfl(sk, 0, 64);
    q[idx] = qv / (sqrtf(sq) + 1e-6f);
    k[idx] = kv / (sqrtf(sk) + 1e-6f);
}

// ---------------- DeltaNet recurrence: 1 wave per (b,head) ----------------
__global__ void delta_kernel(const float* __restrict__ q, const float* __restrict__ k,
                             const float* __restrict__ v, const float* __restrict__ beta,
                             float* __restrict__ o) {
    int bh = blockIdx.x;            // 0..47
    int b = bh / HEADS, hd = bh % HEADS;
    int tid = threadIdx.x;          // 0..63 (column of S)
    __shared__ float kb[64], qb[64];
    float S[64];
#pragma unroll
    for (int r = 0; r < 64; r++) S[r] = 0.f;
    const long base = (long)b * N_TOK * H_SIZE + hd * HDIM;
    for (int t = 0; t < N_TOK; t++) {
        long idx = base + (long)t * H_SIZE + tid;
        float kv = k[idx], qv = q[idx], vv = v[idx];
        float bt = beta[((long)b * N_TOK + t) * HEADS + hd];
        __syncthreads();
        kb[tid] = kv; qb[tid] = qv;
        __syncthreads();
        float dot = 0.f;
#pragma unroll
        for (int r = 0; r < 64; r++) dot += kb[r] * S[r];
        float u = bt * (vv - dot);
        float od = 0.f;
#pragma unroll
        for (int r = 0; r < 64; r++) { S[r] += kb[r] * u; od += qb[r] * S[r]; }
        o[idx] = od;
    }
}

// ---------------- residual with per-(batch,channel) gate ----------------
__global__ void resid_kernel(float* __restrict__ h, const float* __restrict__ tmp,
                             const float* __restrict__ mod, int modStride, int gOff) {
    long i = (long)blockIdx.x * 256 + threadIdx.x;
    if (i >= (long)TOKS * H_SIZE) return;
    int b = (int)(i / (N_TOK * H_SIZE));
    int d = (int)(i % H_SIZE);
    h[i] += mod[(long)b * modStride + gOff + d] * tmp[i];
}

// ---------------- softmax over 8 experts + top2 ----------------
__global__ void softtop2_kernel(float* __restrict__ probs, float* __restrict__ topv,
                                int* __restrict__ topi) {
    int t = blockIdx.x * 256 + threadIdx.x;
    if (t >= TOKS) return;
    float p[E_NUM];
    float mx = -1e30f;
#pragma unroll
    for (int e = 0; e < E_NUM; e++) { p[e] = probs[t * E_NUM + e]; mx = fmaxf(mx, p[e]); }
    float sum = 0.f;
#pragma unroll
    for (int e = 0; e < E_NUM; e++) { p[e] = expf(p[e] - mx); sum += p[e]; }
#pragma unroll
    for (int e = 0; e < E_NUM; e++) { p[e] /= sum; probs[t * E_NUM + e] = p[e]; }
    int i0 = 0;
#pragma unroll
    for (int e = 1; e < E_NUM; e++) if (p[e] > p[i0]) i0 = e;
    int i1 = -1;
#pragma unroll
    for (int e = 0; e < E_NUM; e++) if (e != i0 && (i1 < 0 || p[e] > p[i1])) i1 = e;
    float v0 = p[i0], v1 = p[i1], sv = v0 + v1;
    topi[t * 2] = i0; topi[t * 2 + 1] = i1;
    topv[t * 2] = v0 / sv; topv[t * 2 + 1] = v1 / sv;
}

// ---------------- serial capacity routing (matches reference j-major order) ----------------
__global__ void route_kernel(const int* __restrict__ topi, int* __restrict__ pos,
                             int* __restrict__ slot2tok) {
    int e = threadIdx.x;
    if (e >= E_NUM) return;
    for (int c = 0; c < C_CAP; c++) slot2tok[e * C_CAP + c] = -1;
    int cnt = 0;
    for (int j = 0; j < TOPK; j++)
        for (int t = 0; t < TOKS; t++)
            if (topi[t * 2 + j] == e) {
                int p = cnt++;
                pos[t * 2 + j] = p;
                if (p < C_CAP) slot2tok[e * C_CAP + p] = t;
            }
}

// ---------------- gather tokens into expert capacity slots ----------------
__global__ void gather_kernel(const float* __restrict__ x2, const int* __restrict__ slot2tok,
                              float* __restrict__ xe) {
    int s = blockIdx.x;       // 0..E*C-1
    int tok = slot2tok[s];
    for (int d = threadIdx.x; d < H_SIZE; d += 256)
        xe[(long)s * H_SIZE + d] = (tok >= 0) ? x2[(long)tok * H_SIZE + d] : 0.f;
}

// ---------------- combine expert outputs back to tokens + gated residual ----------------
__global__ void combine_kernel(float* __restrict__ h, const float* __restrict__ ye,
                               const float* __restrict__ topv, const int* __restrict__ topi,
                               const int* __restrict__ pos, const float* __restrict__ mod,
                               int gOff) {
    int t = blockIdx.x;
    int b = t >> 8;
    const float* g = mod + (long)b * 4608 + gOff;
    for (int d = threadIdx.x; d < H_SIZE; d += 256) {
        float acc = 0.f;
#pragma unroll
        for (int j = 0; j < TOPK; j++) {
            int p = pos[t * 2 + j];
            if (p < C_CAP)
                acc += topv[t * 2 + j] * ye[((long)topi[t * 2 + j] * C_CAP + p) * H_SIZE + d];
        }
        h[(long)t * H_SIZE + d] += g[d] * acc;
    }
}

// ---------------- load-balance loss partial sums ----------------
__global__ void lbred_kernel(const float* __restrict__ probs, const int* __restrict__ topi,
                             float* __restrict__ red) {
    int e = blockIdx.x;
    float ps = 0.f, cnt = 0.f;
    for (int tt = threadIdx.x; tt < TOKS; tt += 256) {
        ps += probs[tt * E_NUM + e];
        cnt += (float)((topi[tt * 2] == e) + (topi[tt * 2 + 1] == e));
    }
    __shared__ float sp[256], sc[256];
    sp[threadIdx.x] = ps; sc[threadIdx.x] = cnt;
    __syncthreads();
    for (int s = 128; s; s >>= 1) {
        if (threadIdx.x < s) { sp[threadIdx.x] += sp[threadIdx.x + s]; sc[threadIdx.x] += sc[threadIdx.x + s]; }
        __syncthreads();
    }
    if (threadIdx.x == 0) { red[e] = sp[0]; red[E_NUM + e] = sc[0]; }
}

// ---------------- unpatchify + aux writeout ----------------
__global__ void unpatch_kernel(const float* __restrict__ proj, const float* __restrict__ red,
                               float* __restrict__ out) {
    int i = blockIdx.x * 256 + threadIdx.x; // 0..32767
    if (i < 32768) {
        int b = i >> 13, c = (i >> 10) & 7, ii = (i >> 5) & 31, jj = i & 31;
        int tok = b * 256 + (ii >> 1) * 16 + (jj >> 1);
        int col = (ii & 1) * 16 + (jj & 1) * 8 + c;
        out[i] = proj[tok * 32 + col];
    }
    if (i == 0) {
        float aux = 0.f;
        for (int l = 0; l < DEPTH; l++) {
            float s = 0.f;
            for (int e = 0; e < E_NUM; e++)
                s += (red[l * 16 + E_NUM + e] / (float)(TOKS * TOPK)) * (red[l * 16 + e] / (float)TOKS);
            aux += 0.01f * (float)E_NUM * s;
        }
        out[32768] = aux;
    }
}

extern "C" void kernel_launch(void* const* d_in, const int* in_sizes, int n_in,
                              void* d_out, int out_size, void* d_ws, size_t ws_size,
                              hipStream_t stream) {
    const float* x        = (const float*)d_in[0];
    const float* t        = (const float*)d_in[1];
    const float* Wpe      = (const float*)d_in[2];
    const float* bpe      = (const float*)d_in[3];
    const float* pos_emb  = (const float*)d_in[4];
    const float* Wt1      = (const float*)d_in[5];
    const float* bt1      = (const float*)d_in[6];
    const float* Wt2      = (const float*)d_in[7];
    const float* bt2      = (const float*)d_in[8];
    const float* null_emb = (const float*)d_in[9];
    const float* Wada     = (const float*)d_in[10];
    const float* bada     = (const float*)d_in[11];
    const float* Wq       = (const float*)d_in[12];
    const float* Wk       = (const float*)d_in[13];
    const float* Wv       = (const float*)d_in[14];
    const float* Wb       = (const float*)d_in[15];
    const float* Wo       = (const float*)d_in[16];
    const float* Wg       = (const float*)d_in[17];
    const float* W1       = (const float*)d_in[18];
    const float* b1       = (const float*)d_in[19];
    const float* W2       = (const float*)d_in[20];
    const float* b2       = (const float*)d_in[21];
    const float* Wada_f   = (const float*)d_in[22];
    const float* bada_f   = (const float*)d_in[23];
    const float* Wout     = (const float*)d_in[24];
    const float* bout     = (const float*)d_in[25];
    float* out = (float*)d_out;

    float* ws = (float*)d_ws;
    size_t off = 0;
    auto alloc = [&](size_t n) { float* p = ws + off; off += n; return p; };
    float* h    = alloc((size_t)TOKS * H_SIZE);
    float* hn   = alloc((size_t)TOKS * H_SIZE);
    float* q    = alloc((size_t)TOKS * H_SIZE);
    float* k    = alloc((size_t)TOKS * H_SIZE);
    float* v    = alloc((size_t)TOKS * H_SIZE);
    float* o    = alloc((size_t)TOKS * H_SIZE);
    float* tmp  = alloc((size_t)TOKS * H_SIZE);
    float* beta = alloc((size_t)TOKS * HEADS);
    float* te   = alloc((size_t)BATCH * H_SIZE);
    float* th   = alloc((size_t)BATCH * H_SIZE);
    float* temb = alloc((size_t)BATCH * H_SIZE);
    float* cond = alloc((size_t)BATCH * H_SIZE);
    float* mods = alloc((size_t)BATCH * 6 * H_SIZE);
    float* adaf = alloc((size_t)BATCH * 2 * H_SIZE);
    float* probs = alloc((size_t)TOKS * E_NUM);
    float* topv = alloc((size_t)TOKS * TOPK);
    int* topi   = (int*)alloc((size_t)TOKS * TOPK);
    int* pos    = (int*)alloc((size_t)TOKS * TOPK);
    int* s2t    = (int*)alloc((size_t)E_NUM * C_CAP);
    float* xe   = alloc((size_t)E_NUM * C_CAP * H_SIZE);
    float* h1   = alloc((size_t)E_NUM * C_CAP * FFN_D);
    float* ye   = alloc((size_t)E_NUM * C_CAP * H_SIZE);
    float* red  = alloc(32);

    // ---- embed ----
    patch_kernel<<<dim3(TOKS), dim3(256), 0, stream>>>(x, Wpe, bpe, pos_emb, h);
    te_kernel<<<dim3(12), dim3(256), 0, stream>>>(t, te);
    gemm_naive<<<dim3((BATCH * H_SIZE + 255) / 256), dim3(256), 0, stream>>>(te, Wt1, bt1, th, BATCH, H_SIZE, H_SIZE, 1);
    gemm_naive<<<dim3((BATCH * H_SIZE + 255) / 256), dim3(256), 0, stream>>>(th, Wt2, bt2, temb, BATCH, H_SIZE, H_SIZE, 0);
    cond_kernel<<<dim3(12), dim3(256), 0, stream>>>(temb, null_emb, cond);

    for (int l = 0; l < DEPTH; l++) {
        const float* Wq_l = Wq + (size_t)l * H_SIZE * H_SIZE;
        const float* Wk_l = Wk + (size_t)l * H_SIZE * H_SIZE;
        const float* Wv_l = Wv + (size_t)l * H_SIZE * H_SIZE;
        const float* Wb_l = Wb + (size_t)l * H_SIZE * HEADS;
        const float* Wo_l = Wo + (size_t)l * H_SIZE * H_SIZE;
        const float* Wg_l = Wg + (size_t)l * H_SIZE * E_NUM;
        const float* W1_l = W1 + (size_t)l * E_NUM * H_SIZE * FFN_D;
        const float* b1_l = b1 + (size_t)l * E_NUM * FFN_D;
        const float* W2_l = W2 + (size_t)l * E_NUM * FFN_D * H_SIZE;
        const float* b2_l = b2 + (size_t)l * E_NUM * H_SIZE;

        // adaLN params
        gemm_naive<<<dim3((BATCH * 6 * H_SIZE + 255) / 256), dim3(256), 0, stream>>>(
            cond, Wada + (size_t)l * H_SIZE * 6 * H_SIZE, bada + (size_t)l * 6 * H_SIZE,
            mods, BATCH, 6 * H_SIZE, H_SIZE, 0);

        // attn branch
        ln_mod_kernel<<<dim3(TOKS), dim3(256), 0, stream>>>(h, hn, mods, 6 * H_SIZE, 0, 768);
        gemm_tiled<<<dim3(12, 16, 1), dim3(256), 0, stream>>>(hn, Wq_l, nullptr, q, TOKS, H_SIZE, H_SIZE, 0, 0, 0, 0, 1);
        gemm_tiled<<<dim3(12, 16, 1), dim3(256), 0, stream>>>(hn, Wk_l, nullptr, k, TOKS, H_SIZE, H_SIZE, 0, 0, 0, 0, 1);
        gemm_tiled<<<dim3(12, 16, 1), dim3(256), 0, stream>>>(hn, Wv_l, nullptr, v, TOKS, H_SIZE, H_SIZE, 0, 0, 0, 0, 0);
        gemm_naive<<<dim3((TOKS * HEADS + 255) / 256), dim3(256), 0, stream>>>(hn, Wb_l, nullptr, beta, TOKS, HEADS, H_SIZE, 3);
        headnorm_kernel<<<dim3(TOKS * HEADS), dim3(64), 0, stream>>>(q, k);
        delta_kernel<<<dim3(BATCH * HEADS), dim3(64), 0, stream>>>(q, k, v, beta, o);
        gemm_tiled<<<dim3(12, 16, 1), dim3(256), 0, stream>>>(o, Wo_l, nullptr, tmp, TOKS, H_SIZE, H_SIZE, 0, 0, 0, 0, 0);
        resid_kernel<<<dim3((TOKS * H_SIZE + 255) / 256), dim3(256), 0, stream>>>(h, tmp, mods, 6 * H_SIZE, 2 * 768);

        // MoE branch
        ln_mod_kernel<<<dim3(TOKS), dim3(256), 0, stream>>>(h, hn, mods, 6 * H_SIZE, 3 * 768, 4 * 768);
        gemm_naive<<<dim3((TOKS * E_NUM + 255) / 256), dim3(256), 0, stream>>>(hn, Wg_l, nullptr, probs, TOKS, E_NUM, H_SIZE, 0);
        softtop2_kernel<<<dim3(4), dim3(256), 0, stream>>>(probs, topv, topi);
        route_kernel<<<dim3(1), dim3(64), 0, stream>>>(topi, pos, s2t);
        gather_kernel<<<dim3(E_NUM * C_CAP), dim3(256), 0, stream>>>(hn, s2t, xe);
        gemm_tiled<<<dim3(FFN_D / 64, C_CAP / 64, E_NUM), dim3(256), 0, stream>>>(
            xe, W1_l, b1_l, h1, C_CAP, FFN_D, H_SIZE,
            (long)C_CAP * H_SIZE, (long)H_SIZE * FFN_D, FFN_D, (long)C_CAP * FFN_D, 2);
        gemm_tiled<<<dim3(H_SIZE / 64, C_CAP / 64, E_NUM), dim3(256), 0, stream>>>(
            h1, W2_l, b2_l, ye, C_CAP, H_SIZE, FFN_D,
            (long)C_CAP * FFN_D, (long)FFN_D * H_SIZE, H_SIZE, (long)C_CAP * H_SIZE, 0);
        combine_kernel<<<dim3(TOKS), dim3(256), 0, stream>>>(h, ye, topv, topi, pos, mods, 5 * 768);
        lbred_kernel<<<dim3(E_NUM), dim3(256), 0, stream>>>(probs, topi, red + l * 16);
    }

    // ---- final ----
    gemm_naive<<<dim3((BATCH * 2 * H_SIZE + 255) / 256), dim3(256), 0, stream>>>(
        cond, Wada_f, bada_f, adaf, BATCH, 2 * H_SIZE, H_SIZE, 0);
    ln_mod_kernel<<<dim3(TOKS), dim3(256), 0, stream>>>(h, hn, adaf, 2 * H_SIZE, 0, 768);
    gemm_naive<<<dim3((TOKS * 32 + 255) / 256), dim3(256), 0, stream>>>(hn, Wout, bout, tmp, TOKS, 32, H_SIZE, 0);
    unpatch_kernel<<<dim3(128), dim3(256), 0, stream>>>(tmp, red, out);
}